// Round 1
// baseline (215.627 us; speedup 1.0000x reference)
//
#include <hip/hip_runtime.h>

// ---------------------------------------------------------------------------
// MultiHeadAttention (B=2, E=512, H=8, T=2048, DH=64), fp32 in/out.
// Pipeline (all bf16 MFMA internally):
//   K1 wstd:   weight-standardize Wq/Wk/Wv/Wo -> bf16 [O][I]
//   K2 trans:  x[b][i][t]*mask[t] -> xT[src][b][t][i] bf16   (masks folded here)
//   K3 proj:   Y = Wn @ xT^T + bias, per-head LN fused in epilogue.
//              Q,K written [B][H][T][DH] (Q pre-scaled by 1/181); V written [B][H][DH][T]
//   K4 attn:   one-pass no-max softmax flash attention, out -> xa[B][T][E] bf16
//   K5 oproj:  out = WnO @ xa^T + bo -> fp32 [B][E][T]
// ---------------------------------------------------------------------------

typedef __bf16 bf16;
typedef __bf16 bf16x8 __attribute__((ext_vector_type(8)));
typedef float  f32x4  __attribute__((ext_vector_type(4)));

#define MFMA_BF16(a, b, c) __builtin_amdgcn_mfma_f32_16x16x32_bf16((a), (b), (c), 0, 0, 0)

#define NB   2
#define NE   512
#define NH   8
#define NT   2048
#define NDH  64

__device__ __forceinline__ void gl_lds16(const bf16* g, bf16* l) {
  // async global->LDS, 16B/lane; LDS dest is wave-uniform base + lane*16 (HW)
  __builtin_amdgcn_global_load_lds(
      (const __attribute__((address_space(1))) void*)g,
      (__attribute__((address_space(3))) void*)l, 16, 0, 0);
}

// ---------------- K1: weight standardization -> bf16 ----------------------
__global__ __launch_bounds__(64) void k_wstd(
    const float* __restrict__ Wq, const float* __restrict__ Wk,
    const float* __restrict__ Wv, const float* __restrict__ Wo,
    bf16* __restrict__ out)  // [4][512][512]
{
  const float* W = blockIdx.y == 0 ? Wq : blockIdx.y == 1 ? Wk
                 : blockIdx.y == 2 ? Wv : Wo;
  int row = blockIdx.x, lane = threadIdx.x;
  const float4* p = (const float4*)(W + row * NE) + lane * 2;
  float4 a = p[0], c = p[1];
  float s  = a.x + a.y + a.z + a.w + c.x + c.y + c.z + c.w;
  float ss = a.x*a.x + a.y*a.y + a.z*a.z + a.w*a.w
           + c.x*c.x + c.y*c.y + c.z*c.z + c.w*c.w;
#pragma unroll
  for (int m = 1; m < 64; m <<= 1) { s += __shfl_xor(s, m); ss += __shfl_xor(ss, m); }
  float mean = s * (1.0f / NE);
  float var  = ss * (1.0f / NE) - mean * mean;
  float rstd = rsqrtf(var + 1e-5f);
  bf16x8 o;
  o[0] = (bf16)((a.x - mean) * rstd); o[1] = (bf16)((a.y - mean) * rstd);
  o[2] = (bf16)((a.z - mean) * rstd); o[3] = (bf16)((a.w - mean) * rstd);
  o[4] = (bf16)((c.x - mean) * rstd); o[5] = (bf16)((c.y - mean) * rstd);
  o[6] = (bf16)((c.z - mean) * rstd); o[7] = (bf16)((c.w - mean) * rstd);
  *(bf16x8*)(out + blockIdx.y * (NE * NE) + row * NE + lane * 8) = o;
}

// ---------------- K2: transpose + mask + cast ------------------------------
// x[b][i][t] f32 -> xT[src][b][t][i] bf16, multiplied by per-t mask.
__global__ __launch_bounds__(256) void k_trans(
    const float* __restrict__ q, const float* __restrict__ k,
    const float* __restrict__ v,
    const int* __restrict__ qm, const int* __restrict__ km,
    const int* __restrict__ vm,
    bf16* __restrict__ xT)
{
  int src = blockIdx.z >> 1, b = blockIdx.z & 1;
  const float* x = src == 0 ? q : src == 1 ? k : v;
  const int*   m = src == 0 ? qm : src == 1 ? km : vm;
  x += (size_t)b * NE * NT;
  m += b * NT;
  int t0 = blockIdx.x * 64, i0 = blockIdx.y * 64;
  __shared__ float tile[64][65];
  int tt = threadIdx.x & 63, ii = threadIdx.x >> 6;
#pragma unroll
  for (int i = ii; i < 64; i += 4)
    tile[i][tt] = x[(size_t)(i0 + i) * NT + t0 + tt];
  __syncthreads();
  bf16* o = xT + ((size_t)src * NB + b) * NT * NE;
  int i2 = threadIdx.x & 63, t2 = threadIdx.x >> 6;
#pragma unroll
  for (int t = t2; t < 64; t += 4) {
    float mk = (float)m[t0 + t];
    o[(size_t)(t0 + t) * NE + i0 + i2] = (bf16)(tile[i2][t] * mk);
  }
}

// ---------------- K3: projection GEMM + fused per-head LN ------------------
// Tile 64(M=o) x 128(N=t), BK=64, 4 waves (2x2). grid (16, 8, 6: src*2+b)
__global__ __launch_bounds__(256) void k_proj(
    const bf16* __restrict__ Wn,   // [3+1][512][512]
    const bf16* __restrict__ xT,   // [3][B][T][E]
    const float* __restrict__ bq, const float* __restrict__ bk,
    const float* __restrict__ bv,
    const float* __restrict__ gq, const float* __restrict__ bbq,
    const float* __restrict__ gk, const float* __restrict__ bbk,
    const float* __restrict__ gv, const float* __restrict__ bbv,
    bf16* __restrict__ Qh, bf16* __restrict__ Kh, bf16* __restrict__ Vh)
{
  int src = blockIdx.z >> 1, b = blockIdx.z & 1;
  const bf16* A  = Wn + src * (NE * NE);                  // [512][512]
  const bf16* Bm = xT + ((size_t)src * NB + b) * NT * NE; // [2048][512]
  int m0 = blockIdx.y * 64, n0 = blockIdx.x * 128;
  int h = m0 >> 6;

  __shared__ __align__(16) char smem[64 * 129 * 4 + 2 * 128 * 4]; // 34048 B
  bf16*  Al = (bf16*)smem;            // [64][64]
  bf16*  Bl = (bf16*)(smem + 8192);   // [128][64]
  float* Yl = (float*)smem;           // [64][129] (reuses staging LDS)
  float* mu = (float*)(smem + 64 * 129 * 4);
  float* rs = mu + 128;

  int tid = threadIdx.x, lane = tid & 63, w = tid >> 6;
  int mh = (w & 1) * 32, nh = (w >> 1) * 64;
  f32x4 acc[2][4] = {};

  for (int k0 = 0; k0 < NE; k0 += 64) {
    __syncthreads();
#pragma unroll
    for (int i = 0; i < 2; i++) {  // A: 64x64 bf16 = 8KB
      int row = (w << 4) + (i << 3) + (lane >> 3);
      gl_lds16(A + (m0 + row) * NE + k0 + ((lane & 7) << 3),
               Al + ((w << 4) + (i << 3)) * 64);
    }
#pragma unroll
    for (int i = 0; i < 4; i++) {  // B: 128x64 bf16 = 16KB
      int row = (w << 5) + (i << 3) + (lane >> 3);
      gl_lds16(Bm + (size_t)(n0 + row) * NE + k0 + ((lane & 7) << 3),
               Bl + ((w << 5) + (i << 3)) * 64);
    }
    __syncthreads();
#pragma unroll
    for (int kk = 0; kk < 64; kk += 32) {
      bf16x8 af[2], bfv[4];
#pragma unroll
      for (int ms = 0; ms < 2; ms++)
        af[ms] = *(const bf16x8*)(Al + (mh + ms * 16 + (lane & 15)) * 64 + kk + ((lane >> 4) << 3));
#pragma unroll
      for (int ns = 0; ns < 4; ns++)
        bfv[ns] = *(const bf16x8*)(Bl + (nh + ns * 16 + (lane & 15)) * 64 + kk + ((lane >> 4) << 3));
#pragma unroll
      for (int ms = 0; ms < 2; ms++)
#pragma unroll
        for (int ns = 0; ns < 4; ns++)
          acc[ms][ns] = MFMA_BF16(af[ms], bfv[ns], acc[ms][ns]);
    }
  }

  // ---- epilogue: bias + per-head LN over the 64 o's of this tile ----
  __syncthreads();
  {
    const float* bias = src == 0 ? bq : src == 1 ? bk : bv;
#pragma unroll
    for (int ms = 0; ms < 2; ms++)
#pragma unroll
      for (int ns = 0; ns < 4; ns++)
#pragma unroll
        for (int r = 0; r < 4; r++) {
          int om = mh + ms * 16 + ((lane >> 4) << 2) + r;
          int on = nh + ns * 16 + (lane & 15);
          Yl[om * 129 + on] = acc[ms][ns][r] + bias[m0 + om];
        }
  }
  __syncthreads();
  if (tid < 128) {
    float s = 0.f, ss = 0.f;
#pragma unroll 8
    for (int o = 0; o < 64; o++) { float y = Yl[o * 129 + tid]; s += y; ss += y * y; }
    float mean = s * (1.0f / 64.0f);
    float var  = ss * (1.0f / 64.0f) - mean * mean;
    mu[tid] = mean;
    rs[tid] = rsqrtf(var + 1e-5f);
  }
  __syncthreads();

  if (src < 2) {
    // Q/K -> [B][H][T][DH]; Q pre-scaled by 1/SCALE (SCALE = 512 // sqrt(8) = 181.0)
    float scl = (src == 0) ? (1.0f / 181.0f) : 1.0f;
    const float* g  = src == 0 ? gq  : gk;
    const float* bb = src == 0 ? bbq : bbk;
    bf16* out = (src == 0 ? Qh : Kh) + ((size_t)(b * NH + h) * NT + n0) * NDH;
    int d = tid & 63, tb = tid >> 6;
    float gg = g[d] * scl, bb2 = bb[d] * scl;
#pragma unroll
    for (int t = tb; t < 128; t += 4) {
      float val = (Yl[d * 129 + t] - mu[t]) * rs[t] * gg + bb2;
      out[(size_t)t * NDH + d] = (bf16)val;
    }
  } else {
    // V -> [B][H][DH][T]
    bf16* out = Vh + (size_t)(b * NH + h) * NDH * NT + n0;
    int t = tid & 127, db = tid >> 7;
#pragma unroll
    for (int d = db; d < 64; d += 2) {
      float val = (Yl[d * 129 + t] - mu[t]) * rs[t] * gv[d] + bbv[d];
      out[(size_t)d * NT + t] = (bf16)val;
    }
  }
}

// ---------------- K4: flash attention (one-pass, no-max softmax) -----------
// grid (T/64, B*H), block 256. Q tile 64, K tile 128. Logits tiny (std~0.044)
// so exp without max-subtraction is safe; masked keys contribute exactly 0.
__global__ __launch_bounds__(256) void k_attn(
    const bf16* __restrict__ Qh, const bf16* __restrict__ Kh,
    const bf16* __restrict__ Vh,
    const int* __restrict__ qmask, const int* __restrict__ kmask,
    bf16* __restrict__ xa)  // [B][T][E]
{
  int bh = blockIdx.y, b = bh >> 3, h = bh & 7;
  int q0 = blockIdx.x * 64;
  const bf16* Q = Qh + (size_t)bh * NT * NDH;
  const bf16* K = Kh + (size_t)bh * NT * NDH;
  const bf16* V = Vh + (size_t)bh * NDH * NT;

  __shared__ __align__(16) bf16 Kl[128 * 64];   // [kt][d]
  __shared__ __align__(16) bf16 Vl[64 * 128];   // [d][kt]
  __shared__ __align__(16) bf16 Pl[4 * 16 * 128]; // per-wave [q][kt]

  int tid = threadIdx.x, lane = tid & 63, w = tid >> 6;
  int quad = lane >> 4, l15 = lane & 15;

  // Q fragments (persist across K loop): rows q0+w*16+(lane&15)
  int qrow = q0 + w * 16 + l15;
  bf16x8 aq0 = *(const bf16x8*)(Q + (size_t)qrow * NDH + quad * 8);
  bf16x8 aq1 = *(const bf16x8*)(Q + (size_t)qrow * NDH + 32 + quad * 8);

  f32x4 acco[4] = {};           // out [16q][64d]: 4 d-subtiles
  float den[4] = {0.f, 0.f, 0.f, 0.f};

  for (int k0 = 0; k0 < NT; k0 += 128) {
    __syncthreads();
    // stage K tile: contiguous 16KB from global
#pragma unroll
    for (int i = 0; i < 4; i++)
      gl_lds16(K + (size_t)k0 * NDH + w * 2048 + i * 512 + lane * 8,
               Kl + w * 2048 + i * 512);
    // stage V tile: 64 rows x 256B
#pragma unroll
    for (int i = 0; i < 4; i++) {
      int row = w * 16 + i * 4 + quad;
      gl_lds16(V + (size_t)row * NT + k0 + l15 * 8,
               Vl + (w * 16 + i * 4) * 128);
    }
    __syncthreads();

    // S = Q K^T  (scale folded into Q)
    f32x4 s[8];
#pragma unroll
    for (int n = 0; n < 8; n++) {
      bf16x8 kb0 = *(const bf16x8*)(Kl + (n * 16 + l15) * 64 + quad * 8);
      bf16x8 kb1 = *(const bf16x8*)(Kl + (n * 16 + l15) * 64 + 32 + quad * 8);
      f32x4 z = {};
      z = MFMA_BF16(aq0, kb0, z);
      z = MFMA_BF16(aq1, kb1, z);
      s[n] = z;
    }
    // P = exp(S) * key_mask; accumulate row sums; write P (bf16) for A-operand
#pragma unroll
    for (int n = 0; n < 8; n++) {
      float km = (float)kmask[b * NT + k0 + n * 16 + l15];
#pragma unroll
      for (int r = 0; r < 4; r++) {
        float p = __expf(s[n][r]) * km;
        den[r] += p;
        Pl[w * 2048 + (quad * 4 + r) * 128 + n * 16 + l15] = (bf16)p;
      }
    }
    // O += P @ V   (P per-wave in LDS; no cross-wave barrier needed)
#pragma unroll
    for (int kk = 0; kk < 4; kk++) {
      bf16x8 pa = *(const bf16x8*)(Pl + w * 2048 + l15 * 128 + kk * 32 + quad * 8);
#pragma unroll
      for (int ds = 0; ds < 4; ds++) {
        bf16x8 vb = *(const bf16x8*)(Vl + (ds * 16 + l15) * 128 + kk * 32 + quad * 8);
        acco[ds] = MFMA_BF16(pa, vb, acco[ds]);
      }
    }
  }

  // reduce denominators across the 16 lanes of each quad (cols of D layout)
#pragma unroll
  for (int m = 1; m < 16; m <<= 1)
#pragma unroll
    for (int r = 0; r < 4; r++) den[r] += __shfl_xor(den[r], m);

#pragma unroll
  for (int r = 0; r < 4; r++) {
    int qi = q0 + w * 16 + quad * 4 + r;
    float qm = (float)qmask[b * NT + qi];
    float inv = qm / den[r];  // masked query -> exact 0 (matches reference)
#pragma unroll
    for (int ds = 0; ds < 4; ds++) {
      float val = acco[ds][r] * inv;
      xa[((size_t)b * NT + qi) * NE + h * NDH + ds * 16 + l15] = (bf16)val;
    }
  }
}

// ---------------- K5: output projection ------------------------------------
// out[b][o][t] = WnO @ xa^T + bo.  Tile 64x128, grid (16, 8, 2)
__global__ __launch_bounds__(256) void k_oproj(
    const bf16* __restrict__ A,    // WnO [512][512]
    const bf16* __restrict__ xab,  // [B][T][E]
    const float* __restrict__ bo, float* __restrict__ out)
{
  int b = blockIdx.z;
  const bf16* Bm = xab + (size_t)b * NT * NE;
  int m0 = blockIdx.y * 64, n0 = blockIdx.x * 128;

  __shared__ __align__(16) char smem[24576];
  bf16* Al = (bf16*)smem;           // [64][64]
  bf16* Bl = (bf16*)(smem + 8192);  // [128][64]

  int tid = threadIdx.x, lane = tid & 63, w = tid >> 6;
  int mh = (w & 1) * 32, nh = (w >> 1) * 64;
  f32x4 acc[2][4] = {};

  for (int k0 = 0; k0 < NE; k0 += 64) {
    __syncthreads();
#pragma unroll
    for (int i = 0; i < 2; i++) {
      int row = (w << 4) + (i << 3) + (lane >> 3);
      gl_lds16(A + (m0 + row) * NE + k0 + ((lane & 7) << 3),
               Al + ((w << 4) + (i << 3)) * 64);
    }
#pragma unroll
    for (int i = 0; i < 4; i++) {
      int row = (w << 5) + (i << 3) + (lane >> 3);
      gl_lds16(Bm + (size_t)(n0 + row) * NE + k0 + ((lane & 7) << 3),
               Bl + ((w << 5) + (i << 3)) * 64);
    }
    __syncthreads();
#pragma unroll
    for (int kk = 0; kk < 64; kk += 32) {
      bf16x8 af[2], bfv[4];
#pragma unroll
      for (int ms = 0; ms < 2; ms++)
        af[ms] = *(const bf16x8*)(Al + (mh + ms * 16 + (lane & 15)) * 64 + kk + ((lane >> 4) << 3));
#pragma unroll
      for (int ns = 0; ns < 4; ns++)
        bfv[ns] = *(const bf16x8*)(Bl + (nh + ns * 16 + (lane & 15)) * 64 + kk + ((lane >> 4) << 3));
#pragma unroll
      for (int ms = 0; ms < 2; ms++)
#pragma unroll
        for (int ns = 0; ns < 4; ns++)
          acc[ms][ns] = MFMA_BF16(af[ms], bfv[ns], acc[ms][ns]);
    }
  }

#pragma unroll
  for (int ms = 0; ms < 2; ms++)
#pragma unroll
    for (int ns = 0; ns < 4; ns++)
#pragma unroll
      for (int r = 0; r < 4; r++) {
        int o = m0 + mh + ms * 16 + ((lane >> 4) << 2) + r;
        int t = n0 + nh + ns * 16 + (lane & 15);
        out[(size_t)b * NE * NT + (size_t)o * NT + t] = acc[ms][ns][r] + bo[o];
      }
}

// ---------------------------------------------------------------------------
extern "C" void kernel_launch(void* const* d_in, const int* in_sizes, int n_in,
                              void* d_out, int out_size, void* d_ws, size_t ws_size,
                              hipStream_t stream)
{
  const float* q  = (const float*)d_in[0];
  const float* k  = (const float*)d_in[1];
  const float* v  = (const float*)d_in[2];
  const int*   qm = (const int*)d_in[3];
  const int*   km = (const int*)d_in[4];
  const int*   vm = (const int*)d_in[5];
  const float* Wq = (const float*)d_in[6];  const float* bq = (const float*)d_in[7];
  const float* Wk = (const float*)d_in[8];  const float* bk = (const float*)d_in[9];
  const float* Wv = (const float*)d_in[10]; const float* bv = (const float*)d_in[11];
  const float* Wo = (const float*)d_in[12]; const float* bo = (const float*)d_in[13];
  const float* gq = (const float*)d_in[14]; const float* bbq = (const float*)d_in[15];
  const float* gk = (const float*)d_in[16]; const float* bbk = (const float*)d_in[17];
  const float* gv = (const float*)d_in[18]; const float* bbv = (const float*)d_in[19];
  float* out = (float*)d_out;

  char* wsb = (char*)d_ws;
  bf16* Wn  = (bf16*)(wsb);                        //  2 MiB: 4x[512][512]
  bf16* xT  = (bf16*)(wsb + (2ull  << 20));        // 12 MiB: 3x[B][T][E]
  bf16* Qh  = (bf16*)(wsb + (14ull << 20));        //  4 MiB: [B][H][T][DH]
  bf16* Kh  = (bf16*)(wsb + (18ull << 20));        //  4 MiB
  bf16* Vh  = (bf16*)(wsb + (22ull << 20));        //  4 MiB: [B][H][DH][T]
  bf16* xa  = (bf16*)(wsb + (26ull << 20));        //  4 MiB: [B][T][E]

  k_wstd <<<dim3(512, 4),   64,  0, stream>>>(Wq, Wk, Wv, Wo, Wn);
  k_trans<<<dim3(32, 8, 6), 256, 0, stream>>>(q, k, v, qm, km, vm, xT);
  k_proj <<<dim3(16, 8, 6), 256, 0, stream>>>(Wn, xT, bq, bk, bv,
                                              gq, bbq, gk, bbk, gv, bbv,
                                              Qh, Kh, Vh);
  k_attn <<<dim3(32, 16),   256, 0, stream>>>(Qh, Kh, Vh, qm, km, xa);
  k_oproj<<<dim3(16, 8, 2), 256, 0, stream>>>(Wn + 3 * NE * NE, xa, bo, out);
}

// Round 2
// 178.502 us; speedup vs baseline: 1.2080x; 1.2080x over previous
//
#include <hip/hip_runtime.h>

// ---------------------------------------------------------------------------
// MultiHeadAttention (B=2, E=512, H=8, T=2048, DH=64), fp32 in/out.
//   K1 wstd:   weight-standardize Wq/Wk/Wv/Wo -> bf16 [O][I]
//   K2 trans:  x[b][i][t]*mask[t] -> xT[src][b][t][i] bf16   (masks folded)
//   K3 proj:   Y = Wn @ xT^T + bias, per-head LN fused; XOR-swizzled LDS
//   K4 attn:   wave-split-K flash attention, K/V global->reg, no in-loop barriers
//   K5 oproj:  out = WnO @ xa^T + bo -> fp32; XOR-swizzled LDS
// ---------------------------------------------------------------------------

typedef __bf16 bf16;
typedef __bf16 bf16x8 __attribute__((ext_vector_type(8)));
typedef float  f32x4  __attribute__((ext_vector_type(4)));

#define MFMA_BF16(a, b, c) __builtin_amdgcn_mfma_f32_16x16x32_bf16((a), (b), (c), 0, 0, 0)

#define NB   2
#define NE   512
#define NH   8
#define NT   2048
#define NDH  64

__device__ __forceinline__ void gl_lds16(const bf16* g, bf16* l) {
  // async global->LDS, 16B/lane; LDS dest is wave-uniform base + lane*16 (HW)
  __builtin_amdgcn_global_load_lds(
      (const __attribute__((address_space(1))) void*)g,
      (__attribute__((address_space(3))) void*)l, 16, 0, 0);
}

// ---------------- K1: weight standardization -> bf16 ----------------------
__global__ __launch_bounds__(64) void k_wstd(
    const float* __restrict__ Wq, const float* __restrict__ Wk,
    const float* __restrict__ Wv, const float* __restrict__ Wo,
    bf16* __restrict__ out)  // [4][512][512]
{
  const float* W = blockIdx.y == 0 ? Wq : blockIdx.y == 1 ? Wk
                 : blockIdx.y == 2 ? Wv : Wo;
  int row = blockIdx.x, lane = threadIdx.x;
  const float4* p = (const float4*)(W + row * NE) + lane * 2;
  float4 a = p[0], c = p[1];
  float s  = a.x + a.y + a.z + a.w + c.x + c.y + c.z + c.w;
  float ss = a.x*a.x + a.y*a.y + a.z*a.z + a.w*a.w
           + c.x*c.x + c.y*c.y + c.z*c.z + c.w*c.w;
#pragma unroll
  for (int m = 1; m < 64; m <<= 1) { s += __shfl_xor(s, m); ss += __shfl_xor(ss, m); }
  float mean = s * (1.0f / NE);
  float var  = ss * (1.0f / NE) - mean * mean;
  float rstd = rsqrtf(var + 1e-5f);
  bf16x8 o;
  o[0] = (bf16)((a.x - mean) * rstd); o[1] = (bf16)((a.y - mean) * rstd);
  o[2] = (bf16)((a.z - mean) * rstd); o[3] = (bf16)((a.w - mean) * rstd);
  o[4] = (bf16)((c.x - mean) * rstd); o[5] = (bf16)((c.y - mean) * rstd);
  o[6] = (bf16)((c.z - mean) * rstd); o[7] = (bf16)((c.w - mean) * rstd);
  *(bf16x8*)(out + blockIdx.y * (NE * NE) + row * NE + lane * 8) = o;
}

// ---------------- K2: transpose + mask + cast ------------------------------
__global__ __launch_bounds__(256) void k_trans(
    const float* __restrict__ q, const float* __restrict__ k,
    const float* __restrict__ v,
    const int* __restrict__ qm, const int* __restrict__ km,
    const int* __restrict__ vm,
    bf16* __restrict__ xT)
{
  int src = blockIdx.z >> 1, b = blockIdx.z & 1;
  const float* x = src == 0 ? q : src == 1 ? k : v;
  const int*   m = src == 0 ? qm : src == 1 ? km : vm;
  x += (size_t)b * NE * NT;
  m += b * NT;
  int t0 = blockIdx.x * 64, i0 = blockIdx.y * 64;
  __shared__ float tile[64][65];
  int tt = threadIdx.x & 63, ii = threadIdx.x >> 6;
#pragma unroll
  for (int i = ii; i < 64; i += 4)
    tile[i][tt] = x[(size_t)(i0 + i) * NT + t0 + tt];
  __syncthreads();
  bf16* o = xT + ((size_t)src * NB + b) * NT * NE;
  int i2 = threadIdx.x & 63, t2 = threadIdx.x >> 6;
#pragma unroll
  for (int t = t2; t < 64; t += 4) {
    float mk = (float)m[t0 + t];
    o[(size_t)(t0 + t) * NE + i0 + i2] = (bf16)(tile[i2][t] * mk);
  }
}

// ---------------- K3: projection GEMM + fused per-head LN ------------------
// Tile 64(M=o) x 128(N=t), BK=64, 4 waves (2x2). grid (16, 8, 6: src*2+b)
// LDS tiles XOR-swizzled: slot (row, c) holds global chunk c ^ (row&7).
__global__ __launch_bounds__(256) void k_proj(
    const bf16* __restrict__ Wn,   // [3+1][512][512]
    const bf16* __restrict__ xT,   // [3][B][T][E]
    const float* __restrict__ bq, const float* __restrict__ bk,
    const float* __restrict__ bv,
    const float* __restrict__ gq, const float* __restrict__ bbq,
    const float* __restrict__ gk, const float* __restrict__ bbk,
    const float* __restrict__ gv, const float* __restrict__ bbv,
    bf16* __restrict__ Qh, bf16* __restrict__ Kh, bf16* __restrict__ Vh)
{
  int src = blockIdx.z >> 1, b = blockIdx.z & 1;
  const bf16* A  = Wn + src * (NE * NE);                  // [512][512]
  const bf16* Bm = xT + ((size_t)src * NB + b) * NT * NE; // [2048][512]
  int m0 = blockIdx.y * 64, n0 = blockIdx.x * 128;
  int h = m0 >> 6;

  __shared__ __align__(16) char smem[64 * 129 * 4 + 2 * 128 * 4]; // 34048 B
  bf16*  Al = (bf16*)smem;            // [64][64] swizzled
  bf16*  Bl = (bf16*)(smem + 8192);   // [128][64] swizzled
  float* Yl = (float*)smem;           // [64][129]
  float* mu = (float*)(smem + 64 * 129 * 4);
  float* rs = mu + 128;

  int tid = threadIdx.x, lane = tid & 63, w = tid >> 6;
  int mh = (w & 1) * 32, nh = (w >> 1) * 64;
  f32x4 acc[2][4] = {};

  for (int k0 = 0; k0 < NE; k0 += 64) {
    __syncthreads();
#pragma unroll
    for (int i = 0; i < 2; i++) {  // A: 64x64 bf16 = 8KB
      int row = (w << 4) + (i << 3) + (lane >> 3);
      int chg = (lane & 7) ^ (row & 7);
      gl_lds16(A + (m0 + row) * NE + k0 + (chg << 3),
               Al + ((w << 4) + (i << 3)) * 64);
    }
#pragma unroll
    for (int i = 0; i < 4; i++) {  // B: 128x64 bf16 = 16KB
      int row = (w << 5) + (i << 3) + (lane >> 3);
      int chg = (lane & 7) ^ (row & 7);
      gl_lds16(Bm + (size_t)(n0 + row) * NE + k0 + (chg << 3),
               Bl + ((w << 5) + (i << 3)) * 64);
    }
    __syncthreads();
#pragma unroll
    for (int kk = 0; kk < 64; kk += 32) {
      bf16x8 af[2], bfv[4];
#pragma unroll
      for (int ms = 0; ms < 2; ms++) {
        int row = mh + ms * 16 + (lane & 15);
        af[ms] = *(const bf16x8*)(Al + row * 64 +
                   ((((kk >> 3) + (lane >> 4)) ^ (row & 7)) << 3));
      }
#pragma unroll
      for (int ns = 0; ns < 4; ns++) {
        int row = nh + ns * 16 + (lane & 15);
        bfv[ns] = *(const bf16x8*)(Bl + row * 64 +
                   ((((kk >> 3) + (lane >> 4)) ^ (row & 7)) << 3));
      }
#pragma unroll
      for (int ms = 0; ms < 2; ms++)
#pragma unroll
        for (int ns = 0; ns < 4; ns++)
          acc[ms][ns] = MFMA_BF16(af[ms], bfv[ns], acc[ms][ns]);
    }
  }

  // ---- epilogue: bias + per-head LN over the 64 o's of this tile ----
  __syncthreads();
  {
    const float* bias = src == 0 ? bq : src == 1 ? bk : bv;
#pragma unroll
    for (int ms = 0; ms < 2; ms++)
#pragma unroll
      for (int ns = 0; ns < 4; ns++)
#pragma unroll
        for (int r = 0; r < 4; r++) {
          int om = mh + ms * 16 + ((lane >> 4) << 2) + r;
          int on = nh + ns * 16 + (lane & 15);
          Yl[om * 129 + on] = acc[ms][ns][r] + bias[m0 + om];
        }
  }
  __syncthreads();
  if (tid < 128) {
    float s = 0.f, ss = 0.f;
#pragma unroll 8
    for (int o = 0; o < 64; o++) { float y = Yl[o * 129 + tid]; s += y; ss += y * y; }
    float mean = s * (1.0f / 64.0f);
    float var  = ss * (1.0f / 64.0f) - mean * mean;
    mu[tid] = mean;
    rs[tid] = rsqrtf(var + 1e-5f);
  }
  __syncthreads();

  if (src < 2) {
    float scl = (src == 0) ? (1.0f / 181.0f) : 1.0f;  // SCALE = 512//sqrt(8)
    const float* g  = src == 0 ? gq  : gk;
    const float* bb = src == 0 ? bbq : bbk;
    bf16* out = (src == 0 ? Qh : Kh) + ((size_t)(b * NH + h) * NT + n0) * NDH;
    int d = tid & 63, tb = tid >> 6;
    float gg = g[d] * scl, bb2 = bb[d] * scl;
#pragma unroll
    for (int t = tb; t < 128; t += 4) {
      float val = (Yl[d * 129 + t] - mu[t]) * rs[t] * gg + bb2;
      out[(size_t)t * NDH + d] = (bf16)val;
    }
  } else {
    bf16* out = Vh + (size_t)(b * NH + h) * NDH * NT + n0;
    int t = tid & 127, db = tid >> 7;
#pragma unroll
    for (int d = db; d < 64; d += 2) {
      float val = (Yl[d * 129 + t] - mu[t]) * rs[t] * gv[d] + bbv[d];
      out[(size_t)d * NT + t] = (bf16)val;
    }
  }
}

// ---------------- K4: flash attention v2 -----------------------------------
// grid (T/64, B*H), block 256 = 4 waves. Wave w owns kt subset
// {k0 + w*32 .. +32} of every 128-key tile, for ALL 64 q of the block.
// K/V fragments: global->register (double-buffered), P via per-wave LDS.
// No-max softmax => cross-wave combine is plain addition at the end.
__global__ __launch_bounds__(256, 2) void k_attn(
    const bf16* __restrict__ Qh, const bf16* __restrict__ Kh,
    const bf16* __restrict__ Vh,
    const int* __restrict__ qmask, const int* __restrict__ kmask,
    bf16* __restrict__ xa)  // [B][T][E]
{
  int bh = blockIdx.y, b = bh >> 3, h = bh & 7;
  int q0 = blockIdx.x * 64;
  const bf16* Q = Qh + (size_t)bh * NT * NDH;
  const bf16* K = Kh + (size_t)bh * NT * NDH;
  const bf16* V = Vh + (size_t)bh * NDH * NT;

  __shared__ __align__(16) char smem[2 * 64 * 68 * 4 + 4 * 64 * 4]; // 35840 B
  float* OlA  = (float*)smem;                     // [64][68]
  float* OlB  = (float*)(smem + 64 * 68 * 4);     // [64][68]
  float* denl = (float*)(smem + 2 * 64 * 68 * 4); // [4][64]

  int tid = threadIdx.x, lane = tid & 63, w = tid >> 6;
  int quad = lane >> 4, l15 = lane & 15;
  bf16* Plw = (bf16*)smem + w * (64 * 40);        // per-wave [64 q][32+8 kt]

  // Q fragments (A-operand): rows q0+qs*16+l15, cols hf*32+quad*8
  bf16x8 aq[4][2];
#pragma unroll
  for (int qs = 0; qs < 4; qs++)
#pragma unroll
    for (int hf = 0; hf < 2; hf++)
      aq[qs][hf] = *(const bf16x8*)(Q + (size_t)(q0 + qs * 16 + l15) * NDH + hf * 32 + quad * 8);

  f32x4 acco[4][4] = {};        // [qs][ds] partial O over this wave's keys
  float den[4][4] = {};         // [qs][r] partial denominators

  const int ko = w * 32;        // wave's kt offset within each 128-tile
  const bf16* Kbase = K + (size_t)ko * NDH + quad * 8;
  const bf16* Vbase = V + (size_t)l15 * NT + ko + quad * 8;

  bf16x8 kb00, kb01, kb10, kb11, vb0, vb1, vb2, vb3;
  {
    const bf16* kp = Kbase + (size_t)l15 * NDH;
    kb00 = *(const bf16x8*)(kp);             kb01 = *(const bf16x8*)(kp + 32);
    kb10 = *(const bf16x8*)(kp + 16 * NDH);  kb11 = *(const bf16x8*)(kp + 16 * NDH + 32);
    vb0 = *(const bf16x8*)(Vbase);
    vb1 = *(const bf16x8*)(Vbase + 16 * NT);
    vb2 = *(const bf16x8*)(Vbase + 32 * NT);
    vb3 = *(const bf16x8*)(Vbase + 48 * NT);
  }

  for (int k0 = 0; k0 < NT; k0 += 128) {
    // issue next tile's K/V loads (wrap on last iter; values unused)
    int k1 = (k0 + 128) & (NT - 1);
    bf16x8 n00, n01, n10, n11, nv0, nv1, nv2, nv3;
    {
      const bf16* kp = Kbase + (size_t)(k1 + l15) * NDH;
      n00 = *(const bf16x8*)(kp);             n01 = *(const bf16x8*)(kp + 32);
      n10 = *(const bf16x8*)(kp + 16 * NDH);  n11 = *(const bf16x8*)(kp + 16 * NDH + 32);
      const bf16* vp = Vbase + k1;
      nv0 = *(const bf16x8*)(vp);
      nv1 = *(const bf16x8*)(vp + 16 * NT);
      nv2 = *(const bf16x8*)(vp + 32 * NT);
      nv3 = *(const bf16x8*)(vp + 48 * NT);
    }
    float km0 = (float)kmask[b * NT + k0 + ko + l15];
    float km1 = (float)kmask[b * NT + k0 + ko + 16 + l15];

    // S = Q K^T over this wave's 32 keys (scale folded into Q)
    f32x4 s[4][2];
#pragma unroll
    for (int qs = 0; qs < 4; qs++) {
      f32x4 z0 = {}; z0 = MFMA_BF16(aq[qs][0], kb00, z0); z0 = MFMA_BF16(aq[qs][1], kb01, z0); s[qs][0] = z0;
      f32x4 z1 = {}; z1 = MFMA_BF16(aq[qs][0], kb10, z1); z1 = MFMA_BF16(aq[qs][1], kb11, z1); s[qs][1] = z1;
    }
    // P = exp(S)*mask; den accumulate; stash P (bf16) for A-operand reload
#pragma unroll
    for (int qs = 0; qs < 4; qs++)
#pragma unroll
      for (int n = 0; n < 2; n++) {
        float km = n ? km1 : km0;
#pragma unroll
        for (int r = 0; r < 4; r++) {
          float p = __expf(s[qs][n][r]) * km;
          den[qs][r] += p;
          Plw[(qs * 16 + quad * 4 + r) * 40 + n * 16 + l15] = (bf16)p;
        }
      }
    // O += P @ V^T over this wave's 32 keys
#pragma unroll
    for (int qs = 0; qs < 4; qs++) {
      bf16x8 pa = *(const bf16x8*)(Plw + (qs * 16 + l15) * 40 + quad * 8);
      acco[qs][0] = MFMA_BF16(pa, vb0, acco[qs][0]);
      acco[qs][1] = MFMA_BF16(pa, vb1, acco[qs][1]);
      acco[qs][2] = MFMA_BF16(pa, vb2, acco[qs][2]);
      acco[qs][3] = MFMA_BF16(pa, vb3, acco[qs][3]);
    }
    kb00 = n00; kb01 = n01; kb10 = n10; kb11 = n11;
    vb0 = nv0; vb1 = nv1; vb2 = nv2; vb3 = nv3;
  }

  // reduce den across the 16 columns (l15) of each quad
#pragma unroll
  for (int m = 1; m < 16; m <<= 1)
#pragma unroll
    for (int qs = 0; qs < 4; qs++)
#pragma unroll
      for (int r = 0; r < 4; r++)
        den[qs][r] += __shfl_xor(den[qs][r], m);

  __syncthreads();  // all waves done with Plw; Ol buffers overlay that space
  if (l15 == 0)
#pragma unroll
    for (int qs = 0; qs < 4; qs++)
#pragma unroll
      for (int r = 0; r < 4; r++)
        denl[w * 64 + qs * 16 + quad * 4 + r] = den[qs][r];

  float* Obuf = (w < 2) ? OlA : OlB;
  if ((w & 1) == 0) {
#pragma unroll
    for (int qs = 0; qs < 4; qs++)
#pragma unroll
      for (int ds = 0; ds < 4; ds++)
#pragma unroll
        for (int r = 0; r < 4; r++)
          Obuf[(qs * 16 + quad * 4 + r) * 68 + ds * 16 + l15] = acco[qs][ds][r];
  }
  __syncthreads();
  if (w & 1) {
#pragma unroll
    for (int qs = 0; qs < 4; qs++)
#pragma unroll
      for (int ds = 0; ds < 4; ds++)
#pragma unroll
        for (int r = 0; r < 4; r++)
          Obuf[(qs * 16 + quad * 4 + r) * 68 + ds * 16 + l15] += acco[qs][ds][r];
  }
  __syncthreads();

  // output: wave w writes q rows w*16..w*16+15; lane = d
#pragma unroll
  for (int i = 0; i < 16; i++) {
    int ql = w * 16 + i;
    float dtot = denl[ql] + denl[64 + ql] + denl[128 + ql] + denl[192 + ql];
    float qm = (float)qmask[b * NT + q0 + ql];
    float inv = qm / dtot;   // masked query -> exact 0 (matches reference)
    float val = (OlA[ql * 68 + lane] + OlB[ql * 68 + lane]) * inv;
    xa[((size_t)b * NT + q0 + ql) * NE + h * NDH + lane] = (bf16)val;
  }
}

// ---------------- K5: output projection ------------------------------------
__global__ __launch_bounds__(256) void k_oproj(
    const bf16* __restrict__ A,    // WnO [512][512]
    const bf16* __restrict__ xab,  // [B][T][E]
    const float* __restrict__ bo, float* __restrict__ out)
{
  int b = blockIdx.z;
  const bf16* Bm = xab + (size_t)b * NT * NE;
  int m0 = blockIdx.y * 64, n0 = blockIdx.x * 128;

  __shared__ __align__(16) char smem[24576];
  bf16* Al = (bf16*)smem;           // [64][64] swizzled
  bf16* Bl = (bf16*)(smem + 8192);  // [128][64] swizzled

  int tid = threadIdx.x, lane = tid & 63, w = tid >> 6;
  int mh = (w & 1) * 32, nh = (w >> 1) * 64;
  f32x4 acc[2][4] = {};

  for (int k0 = 0; k0 < NE; k0 += 64) {
    __syncthreads();
#pragma unroll
    for (int i = 0; i < 2; i++) {
      int row = (w << 4) + (i << 3) + (lane >> 3);
      int chg = (lane & 7) ^ (row & 7);
      gl_lds16(A + (m0 + row) * NE + k0 + (chg << 3),
               Al + ((w << 4) + (i << 3)) * 64);
    }
#pragma unroll
    for (int i = 0; i < 4; i++) {
      int row = (w << 5) + (i << 3) + (lane >> 3);
      int chg = (lane & 7) ^ (row & 7);
      gl_lds16(Bm + (size_t)(n0 + row) * NE + k0 + (chg << 3),
               Bl + ((w << 5) + (i << 3)) * 64);
    }
    __syncthreads();
#pragma unroll
    for (int kk = 0; kk < 64; kk += 32) {
      bf16x8 af[2], bfv[4];
#pragma unroll
      for (int ms = 0; ms < 2; ms++) {
        int row = mh + ms * 16 + (lane & 15);
        af[ms] = *(const bf16x8*)(Al + row * 64 +
                   ((((kk >> 3) + (lane >> 4)) ^ (row & 7)) << 3));
      }
#pragma unroll
      for (int ns = 0; ns < 4; ns++) {
        int row = nh + ns * 16 + (lane & 15);
        bfv[ns] = *(const bf16x8*)(Bl + row * 64 +
                   ((((kk >> 3) + (lane >> 4)) ^ (row & 7)) << 3));
      }
#pragma unroll
      for (int ms = 0; ms < 2; ms++)
#pragma unroll
        for (int ns = 0; ns < 4; ns++)
          acc[ms][ns] = MFMA_BF16(af[ms], bfv[ns], acc[ms][ns]);
    }
  }

#pragma unroll
  for (int ms = 0; ms < 2; ms++)
#pragma unroll
    for (int ns = 0; ns < 4; ns++)
#pragma unroll
      for (int r = 0; r < 4; r++) {
        int o = m0 + mh + ms * 16 + ((lane >> 4) << 2) + r;
        int t = n0 + nh + ns * 16 + (lane & 15);
        out[(size_t)b * NE * NT + (size_t)o * NT + t] = acc[ms][ns][r] + bo[o];
      }
}

// ---------------------------------------------------------------------------
extern "C" void kernel_launch(void* const* d_in, const int* in_sizes, int n_in,
                              void* d_out, int out_size, void* d_ws, size_t ws_size,
                              hipStream_t stream)
{
  const float* q  = (const float*)d_in[0];
  const float* k  = (const float*)d_in[1];
  const float* v  = (const float*)d_in[2];
  const int*   qm = (const int*)d_in[3];
  const int*   km = (const int*)d_in[4];
  const int*   vm = (const int*)d_in[5];
  const float* Wq = (const float*)d_in[6];  const float* bq = (const float*)d_in[7];
  const float* Wk = (const float*)d_in[8];  const float* bk = (const float*)d_in[9];
  const float* Wv = (const float*)d_in[10]; const float* bv = (const float*)d_in[11];
  const float* Wo = (const float*)d_in[12]; const float* bo = (const float*)d_in[13];
  const float* gq = (const float*)d_in[14]; const float* bbq = (const float*)d_in[15];
  const float* gk = (const float*)d_in[16]; const float* bbk = (const float*)d_in[17];
  const float* gv = (const float*)d_in[18]; const float* bbv = (const float*)d_in[19];
  float* out = (float*)d_out;

  char* wsb = (char*)d_ws;
  bf16* Wn  = (bf16*)(wsb);                        //  2 MiB: 4x[512][512]
  bf16* xT  = (bf16*)(wsb + (2ull  << 20));        // 12 MiB: 3x[B][T][E]
  bf16* Qh  = (bf16*)(wsb + (14ull << 20));        //  4 MiB: [B][H][T][DH]
  bf16* Kh  = (bf16*)(wsb + (18ull << 20));        //  4 MiB
  bf16* Vh  = (bf16*)(wsb + (22ull << 20));        //  4 MiB: [B][H][DH][T]
  bf16* xa  = (bf16*)(wsb + (26ull << 20));        //  4 MiB: [B][T][E]

  k_wstd <<<dim3(512, 4),   64,  0, stream>>>(Wq, Wk, Wv, Wo, Wn);
  k_trans<<<dim3(32, 8, 6), 256, 0, stream>>>(q, k, v, qm, km, vm, xT);
  k_proj <<<dim3(16, 8, 6), 256, 0, stream>>>(Wn, xT, bq, bk, bv,
                                              gq, bbq, gk, bbk, gv, bbv,
                                              Qh, Kh, Vh);
  k_attn <<<dim3(32, 16),   256, 0, stream>>>(Qh, Kh, Vh, qm, km, xa);
  k_oproj<<<dim3(16, 8, 2), 256, 0, stream>>>(Wn + 3 * NE * NE, xa, bo, out);
}